// Round 5
// baseline (145.918 us; speedup 1.0000x reference)
//
#include <hip/hip_runtime.h>

typedef unsigned long long u64;

#define CSC 2.8853900817779268f   // 2*log2(e): tanh(x) = 1 - 2/(exp2(x*CSC)+1)
#define NBIN 4096
#define CAP  256
#define PB   128
#define MAXJ 16                   // select supports N <= 16*4096
#define LP   68                   // LDS tile pitch in floats (16B-aligned, bank-spread)

// ---------- sortable key packing ----------
__device__ __forceinline__ unsigned ord32(float f) {
  unsigned u = __float_as_uint(f);
  return (u & 0x80000000u) ? ~u : (u | 0x80000000u);
}
// max-key: descending score, ties -> ascending index (jax.lax.top_k semantics)
__device__ __forceinline__ u64 packMax(float f, int n) {
  return ((u64)ord32(f) << 32) | (unsigned)(~(unsigned)n);
}

// ================= prep =================
// ipET [64][N]  TRANSPOSED item exp-projection: ipET[d][n] = exp2(CSC*(item@Wi.T)[n,d])
// bpE  [B][64]  basket exp-projection, b-major
__global__ void __launch_bounds__(128)
prep_kernel(const float* __restrict__ basket, const float* __restrict__ item,
            const float* __restrict__ Wb, const float* __restrict__ Wi,
            float* __restrict__ ipET, float* __restrict__ bpE,
            int N, int B, int nItemBlk) {
  __shared__ float WL[4096];
  int tid = threadIdx.x;

  if (blockIdx.x >= nItemBlk) {                // 4 basket blocks
    for (int i = tid; i < 4096; i += PB) WL[i] = Wb[i];
    __syncthreads();
    int which = blockIdx.x - nItemBlk;
    int seg = (B * 64 + 3) / 4;
    int lo = which * seg, hi = min(lo + seg, B * 64);
    for (int idx = lo + tid; idx < hi; idx += PB) {
      int b = idx >> 6, d = idx & 63;
      float acc = 0.f;
#pragma unroll
      for (int e = 0; e < 64; ++e) acc = fmaf(basket[b * 64 + e], WL[d * 64 + e], acc);
      bpE[idx] = __builtin_amdgcn_exp2f(acc * CSC);   // bpE[b][d]
    }
    return;
  }

  for (int i = tid; i < 4096; i += PB) WL[i] = Wi[i];
  __syncthreads();
  int n = blockIdx.x * PB + tid;
  if (n >= N) return;

  float row[64];
  const float4* p = (const float4*)(item + (size_t)n * 64);
#pragma unroll
  for (int i = 0; i < 16; ++i) {
    float4 t = p[i];
    row[4 * i] = t.x; row[4 * i + 1] = t.y; row[4 * i + 2] = t.z; row[4 * i + 3] = t.w;
  }
#pragma unroll
  for (int q = 0; q < 16; ++q) {
    float a0 = 0.f, a1 = 0.f, a2 = 0.f, a3 = 0.f;
#pragma unroll
    for (int e = 0; e < 64; ++e) {
      float re = row[e];
      a0 = fmaf(re, WL[(4 * q + 0) * 64 + e], a0);
      a1 = fmaf(re, WL[(4 * q + 1) * 64 + e], a1);
      a2 = fmaf(re, WL[(4 * q + 2) * 64 + e], a2);
      a3 = fmaf(re, WL[(4 * q + 3) * 64 + e], a3);
    }
    // transposed, coalesced per-d stores
    ipET[(size_t)(4 * q + 0) * N + n] = __builtin_amdgcn_exp2f(a0 * CSC);
    ipET[(size_t)(4 * q + 1) * N + n] = __builtin_amdgcn_exp2f(a1 * CSC);
    ipET[(size_t)(4 * q + 2) * N + n] = __builtin_amdgcn_exp2f(a2 * CSC);
    ipET[(size_t)(4 * q + 3) * N + n] = __builtin_amdgcn_exp2f(a3 * CSC);
  }
}

// ================= scores: lane = basket, ei via scalar loads =================
// block = 256 thr: waves {0,1} -> n-sub [0,32), waves {2,3} -> [32,64); lane+64*(w&1) = basket
__global__ void __launch_bounds__(256, 4)
scores_kernel(const float* __restrict__ ipET, const float* __restrict__ bpE,
              const float* __restrict__ v, float* __restrict__ scores, int N) {
  __shared__ float tile[128 * LP];
  int tid = threadIdx.x;
  int lane = tid & 63, w = tid >> 6;
  int bl = ((w & 1) << 6) | lane;          // basket 0..127 (per-lane)
  int nsub = (w >> 1) << 5;                // 0 or 32 (wave-uniform)
  int chunk = blockIdx.x << 6;             // 64 items per block

  // eb: per-lane basket exp-projection, resident in 64 VGPRs
  float eb[64];
  {
    const float4* ep = (const float4*)(bpE + (size_t)bl * 64);
#pragma unroll
    for (int i = 0; i < 16; ++i) {
      float4 t = ep[i];
      eb[4 * i] = t.x; eb[4 * i + 1] = t.y; eb[4 * i + 2] = t.z; eb[4 * i + 3] = t.w;
    }
  }

  double sv = 0.0;
#pragma unroll
  for (int d = 0; d < 64; ++d) sv += (double)v[d];   // uniform, one-time

  for (int nb = 0; nb < 4; ++nb) {                   // 4 batches of 8 items
    int n0 = __builtin_amdgcn_readfirstlane(chunk + nsub + nb * 8);
    const float* base = ipET + n0;                   // uniform -> s_load path

    double acc[8];
#pragma unroll
    for (int j = 0; j < 8; ++j) acc[j] = 0.0;

#pragma unroll
    for (int half = 0; half < 2; ++half) {           // caps live-v SGPRs
#pragma unroll
      for (int q = 0; q < 4; ++q) {                  // f64 fold every 8 d
        float gs[8];
#pragma unroll
        for (int j = 0; j < 8; ++j) gs[j] = 0.f;
#pragma unroll
        for (int p = 0; p < 4; ++p) {                // pairs (d0,d0+1)
          int d0 = half * 32 + q * 8 + p * 2, d1 = d0 + 1;
          const float* e0 = base + (size_t)d0 * N;   // 8 consecutive -> s_load_dwordx8
          const float* e1 = base + (size_t)d1 * N;
          float vd0 = v[d0], vd1 = v[d1];            // sgpr
          float eb0 = eb[d0], eb1 = eb[d1];          // vgpr
#pragma unroll
          for (int j = 0; j < 8; ++j) {
            float x0 = fmaf(eb0, e0[j], 1.0f);       // (1+E0)
            float x1 = fmaf(eb1, e1[j], 1.0f);       // (1+E1)
            float den = x0 * x1;
            float num = vd0 * x1;
            num = fmaf(vd1, x0, num);                // v0*x1 + v1*x0
            float r = __builtin_amdgcn_rcpf(den);    // 1 rcp per 2 terms
            gs[j] = fmaf(num, r, gs[j]);
          }
        }
#pragma unroll
        for (int j = 0; j < 8; ++j) acc[j] += (double)gs[j];
      }
    }

    int nloc = nsub + nb * 8;
    float* tp = tile + bl * LP + nloc;
    float r0 = (float)(sv - 2.0 * acc[0]), r1 = (float)(sv - 2.0 * acc[1]);
    float r2 = (float)(sv - 2.0 * acc[2]), r3 = (float)(sv - 2.0 * acc[3]);
    float r4 = (float)(sv - 2.0 * acc[4]), r5 = (float)(sv - 2.0 * acc[5]);
    float r6 = (float)(sv - 2.0 * acc[6]), r7 = (float)(sv - 2.0 * acc[7]);
    *(float4*)(tp)     = make_float4(r0, r1, r2, r3);
    *(float4*)(tp + 4) = make_float4(r4, r5, r6, r7);
  }
  __syncthreads();

  // flush tile -> scores[b][chunk..chunk+63], coalesced
  int row = tid >> 1, c0 = (tid & 1) << 5;
#pragma unroll
  for (int q2 = 0; q2 < 8; ++q2) {
    int c = c0 + q2 * 4;
    int gn = chunk + c;
    float4 val = *(float4*)(tile + row * LP + c);
    if (gn + 3 < N) {
      *(float4*)(scores + (size_t)row * N + gn) = val;
    } else {
      float vv[4] = {val.x, val.y, val.z, val.w};
#pragma unroll
      for (int e = 0; e < 4; ++e)
        if (gn + e < N) scores[(size_t)row * N + gn + e] = vv[e];
    }
  }
}

// ================= select: whole pipeline in ONE kernel (1 block = 1 row) =================
__global__ void __launch_bounds__(1024)
select_kernel(const float* __restrict__ scores, const float* __restrict__ v,
              int* __restrict__ out, int N, int B, int K) {
  __shared__ int lh[NBIN];
  __shared__ int part[64];
  __shared__ u64 candP[CAP], candN[CAP];
  __shared__ int cntP, cntN, hHi, hLo;
  int tid = threadIdx.x, b = blockIdx.x;
  const float* row = scores + (size_t)b * N;

  for (int i = tid; i < NBIN; i += 1024) lh[i] = 0;
  if (tid == 0) { cntP = 0; cntN = 0; }

  // |score| < R = sum|v_d| strictly (|tanh|<1) -> linear bins over [-R, R]
  float R = 0.f;
#pragma unroll
  for (int d = 0; d < 64; ++d) R += fabsf(v[d]);     // uniform
  float invW = (float)NBIN / (2.f * R);
  __syncthreads();

  // pass 1: load into REGISTERS + histogram
  float4 v4[MAXJ];
#pragma unroll
  for (int j = 0; j < MAXJ; ++j) {
    int f4 = j * 1024 + tid;
    if (j * 4096 < N && f4 * 4 < N) {
      float4 s4 = *(const float4*)(row + (size_t)f4 * 4);
      v4[j] = s4;
      int n0 = f4 * 4;
      float ss[4] = {s4.x, s4.y, s4.z, s4.w};
#pragma unroll
      for (int c = 0; c < 4; ++c) {
        if (n0 + c < N) {
          int bi = (int)((ss[c] + R) * invW);
          bi = bi < 0 ? 0 : (bi > NBIN - 1 ? NBIN - 1 : bi);
          atomicAdd(&lh[bi], 1);
        }
      }
    }
  }
  __syncthreads();

  if (tid < 64) {                  // 64-bin chunk sums
    int s = 0;
    for (int jj = 0; jj < 64; ++jj) s += lh[tid * 64 + jj];
    part[tid] = s;
  }
  __syncthreads();
  if (tid == 0) {                  // top threshold bin
    int cum = 0, c = 63;
    for (; c > 0; --c) { if (cum + part[c] >= K) break; cum += part[c]; }
    int hh = c * 64 + 63;
    for (;; --hh) { cum += lh[hh]; if (cum >= K || hh == 0) break; }
    hHi = hh;
  }
  if (tid == 1) {                  // bottom threshold bin
    int cum = 0, c = 0;
    for (; c < 63; ++c) { if (cum + part[c] >= K) break; cum += part[c]; }
    int hl = c * 64;
    for (;; ++hl) { cum += lh[hl]; if (cum >= K || hl == NBIN - 1) break; }
    hLo = hl;
  }
  __syncthreads();
  int hi = hHi, lo = hLo;

  // pass 2: compact from registers (no memory re-read)
#pragma unroll
  for (int j = 0; j < MAXJ; ++j) {
    int f4 = j * 1024 + tid;
    if (j * 4096 < N && f4 * 4 < N) {
      int n0 = f4 * 4;
      float ss[4] = {v4[j].x, v4[j].y, v4[j].z, v4[j].w};
#pragma unroll
      for (int c = 0; c < 4; ++c) {
        if (n0 + c < N) {
          float s = ss[c];
          int bi = (int)((s + R) * invW);
          bi = bi < 0 ? 0 : (bi > NBIN - 1 ? NBIN - 1 : bi);
          if (bi >= hi) { int i = atomicAdd(&cntP, 1); if (i < CAP) candP[i] = packMax(s, n0 + c); }
          if (bi <= lo) { int i = atomicAdd(&cntN, 1); if (i < CAP) candN[i] = packMax(s, n0 + c) ^ 0xFFFFFFFFull; }
        }
      }
    }
  }
  __syncthreads();

  // exact rank, O(C^2); keys unique -> ranks unique & complete
  int tP = cntP < CAP ? cntP : CAP;
  int tN = cntN < CAP ? cntN : CAP;
  int* pos = out + (size_t)b * K;
  int* neg = out + (size_t)B * K + (size_t)b * K;
  for (int i = tid; i < tP; i += 1024) {
    u64 key = candP[i]; int r = 0;
    for (int jj = 0; jj < tP; ++jj) r += (candP[jj] > key);
    if (r < K) pos[r] = (int)(~(unsigned)key);
  }
  for (int i = tid; i < tN; i += 1024) {
    u64 key = candN[i]; int r = 0;
    for (int jj = 0; jj < tN; ++jj) r += (candN[jj] < key);
    if (r < K) neg[r] = (int)(unsigned)key;
  }
}

extern "C" void kernel_launch(void* const* d_in, const int* in_sizes, int n_in,
                              void* d_out, int out_size, void* d_ws, size_t ws_size,
                              hipStream_t stream) {
  const float* basket = (const float*)d_in[0];
  const float* item   = (const float*)d_in[1];
  const float* Wb     = (const float*)d_in[2];
  const float* Wi     = (const float*)d_in[3];
  const float* v      = (const float*)d_in[4];
  int D = in_sizes[4];           // 64
  int B = in_sizes[0] / D;       // 128
  int N = in_sizes[1] / D;       // 50000
  int K = out_size / (2 * B);    // 50

  float* scores = (float*)d_ws;                         // B*N floats = 25.6 MB
  float* ipET   = scores + (size_t)B * N;               // 64*N floats = 12.8 MB
  float* bpE    = ipET + (size_t)64 * N;                // B*64 floats = 32 KB

  int nItemBlk = (N + PB - 1) / PB;
  prep_kernel<<<dim3(nItemBlk + 4), dim3(PB), 0, stream>>>(basket, item, Wb, Wi, ipET, bpE, N, B, nItemBlk);

  int nChunk = (N + 63) / 64;
  scores_kernel<<<dim3(nChunk), dim3(256), 0, stream>>>(ipET, bpE, v, scores, N);

  select_kernel<<<dim3(B), dim3(1024), 0, stream>>>(scores, v, (int*)d_out, N, B, K);
}

// Round 6
// 130.825 us; speedup vs baseline: 1.1154x; 1.1154x over previous
//
#include <hip/hip_runtime.h>

typedef unsigned long long u64;

#define CSC 2.8853900817779268f   // 2*log2(e): tanh(x) = 1 - 2/(exp2(x*CSC)+1)
#define NBIN 4096
#define CAP  256
#define BT   16
#define MAXJ 16                   // select supports N <= 16*4096

// ---------- sortable key packing ----------
__device__ __forceinline__ unsigned ord32(float f) {
  unsigned u = __float_as_uint(f);
  return (u & 0x80000000u) ? ~u : (u | 0x80000000u);
}
// max-key: descending score, ties -> ascending index (jax.lax.top_k semantics)
__device__ __forceinline__ u64 packMax(float f, int n) {
  return ((u64)ord32(f) << 32) | (unsigned)(~(unsigned)n);
}

// ================= prep: E = exp2(CSC * proj) =================
// ipE [N][64] row-major; bpE [B][64] b-major. 2 threads per item (split-d).
__global__ void __launch_bounds__(256)
prep_kernel(const float* __restrict__ basket, const float* __restrict__ item,
            const float* __restrict__ Wb, const float* __restrict__ Wi,
            float* __restrict__ ipE, float* __restrict__ bpE,
            int N, int B, int nItemBlk) {
  __shared__ float WL[4096];
  int tid = threadIdx.x;

  if (blockIdx.x >= nItemBlk) {                // basket blocks (4096 outputs each)
    for (int i = tid; i < 4096; i += 256) WL[i] = Wb[i];
    __syncthreads();
    int which = blockIdx.x - nItemBlk;
    int lo = which * 4096, hi = min(lo + 4096, B * 64);
    for (int idx = lo + tid; idx < hi; idx += 256) {
      int b = idx >> 6, d = idx & 63;
      float acc = 0.f;
#pragma unroll
      for (int e = 0; e < 64; ++e) acc = fmaf(basket[b * 64 + e], WL[d * 64 + e], acc);
      bpE[idx] = __builtin_amdgcn_exp2f(acc * CSC);   // bpE[b][d]
    }
    return;
  }

  for (int i = tid; i < 4096; i += 256) WL[i] = Wi[i];
  __syncthreads();
  int it = tid & 127, dh = tid >> 7;           // 2 threads per item, 32 d each
  int n = blockIdx.x * 128 + it;
  if (n >= N) return;

  float row[64];
  const float4* p = (const float4*)(item + (size_t)n * 64);
#pragma unroll
  for (int i = 0; i < 16; ++i) {
    float4 t = p[i];
    row[4 * i] = t.x; row[4 * i + 1] = t.y; row[4 * i + 2] = t.z; row[4 * i + 3] = t.w;
  }
  int dbase = dh * 32;
#pragma unroll
  for (int q = 0; q < 8; ++q) {                // 4 d's per step
    int d0 = dbase + q * 4;
    float a0 = 0.f, a1 = 0.f, a2 = 0.f, a3 = 0.f;
#pragma unroll
    for (int e = 0; e < 64; ++e) {
      float re = row[e];
      a0 = fmaf(re, WL[(d0 + 0) * 64 + e], a0);
      a1 = fmaf(re, WL[(d0 + 1) * 64 + e], a1);
      a2 = fmaf(re, WL[(d0 + 2) * 64 + e], a2);
      a3 = fmaf(re, WL[(d0 + 3) * 64 + e], a3);
    }
    float4 o;
    o.x = __builtin_amdgcn_exp2f(a0 * CSC);
    o.y = __builtin_amdgcn_exp2f(a1 * CSC);
    o.z = __builtin_amdgcn_exp2f(a2 * CSC);
    o.w = __builtin_amdgcn_exp2f(a3 * CSC);
    *(float4*)(ipE + (size_t)n * 64 + d0) = o;
  }
}

// ================= scores: round-3 structure + paired rcp =================
__global__ void __launch_bounds__(256)
scores_kernel(const float* __restrict__ ipE, const float* __restrict__ bpE,
              const float* __restrict__ v, float* __restrict__ scores, int N, int B) {
  int tid = threadIdx.x;
  int b0 = blockIdx.y * BT;
  if (b0 > B - BT) b0 = B - BT;              // duplicate-safe clamp
  int n = blockIdx.x * 256 + tid;
  if (n >= N) return;

  float ei[64];
  const float4* p = (const float4*)(ipE + (size_t)n * 64);
#pragma unroll
  for (int i = 0; i < 16; ++i) {
    float4 t = p[i];
    ei[4 * i] = t.x; ei[4 * i + 1] = t.y; ei[4 * i + 2] = t.z; ei[4 * i + 3] = t.w;
  }

  double sv = 0.0;
#pragma unroll
  for (int d = 0; d < 64; ++d) sv += (double)v[d];   // uniform -> s_load

#pragma unroll 2
  for (int b = 0; b < BT; ++b) {
    const float* eb = bpE + (size_t)(b0 + b) * 64;   // uniform -> s_load_dwordx8
    double acc = 0.0;
#pragma unroll
    for (int g = 0; g < 8; ++g) {                    // f64 fold every 8 d
      float gs = 0.f;
#pragma unroll
      for (int pp = 0; pp < 4; ++pp) {               // pairs (d0, d0+1)
        int d0 = g * 8 + pp * 2, d1 = d0 + 1;
        float x0 = fmaf(eb[d0], ei[d0], 1.0f);       // 1 + exp2(b+i) via product
        float x1 = fmaf(eb[d1], ei[d1], 1.0f);
        float den = x0 * x1;
        float num = v[d0] * x1;
        num = fmaf(v[d1], x0, num);                  // v0*x1 + v1*x0
        float r = __builtin_amdgcn_rcpf(den);        // 1 rcp per 2 terms
        gs = fmaf(num, r, gs);
      }
      acc += (double)gs;
    }
    scores[(size_t)(b0 + b) * N + n] = (float)(sv - 2.0 * acc);
  }
}

// ================= select: whole pipeline in ONE kernel (1 block = 1 row) =================
__global__ void __launch_bounds__(1024)
select_kernel(const float* __restrict__ scores, const float* __restrict__ v,
              int* __restrict__ out, int N, int B, int K) {
  __shared__ int lh[NBIN];
  __shared__ int part[64];
  __shared__ u64 candP[CAP], candN[CAP];
  __shared__ int cntP, cntN, hHi, hLo;
  int tid = threadIdx.x, b = blockIdx.x;
  const float* row = scores + (size_t)b * N;

  for (int i = tid; i < NBIN; i += 1024) lh[i] = 0;
  if (tid == 0) { cntP = 0; cntN = 0; }

  // |score| < R = sum|v_d| strictly (|tanh|<1) -> linear bins over [-R, R]
  float R = 0.f;
#pragma unroll
  for (int d = 0; d < 64; ++d) R += fabsf(v[d]);     // uniform
  float invW = (float)NBIN / (2.f * R);
  __syncthreads();

  // pass 1: load into REGISTERS + histogram
  float4 v4[MAXJ];
#pragma unroll
  for (int j = 0; j < MAXJ; ++j) {
    int f4 = j * 1024 + tid;
    if (j * 4096 < N && f4 * 4 < N) {
      float4 s4 = *(const float4*)(row + (size_t)f4 * 4);
      v4[j] = s4;
      int n0 = f4 * 4;
      float ss[4] = {s4.x, s4.y, s4.z, s4.w};
#pragma unroll
      for (int c = 0; c < 4; ++c) {
        if (n0 + c < N) {
          int bi = (int)((ss[c] + R) * invW);
          bi = bi < 0 ? 0 : (bi > NBIN - 1 ? NBIN - 1 : bi);
          atomicAdd(&lh[bi], 1);
        }
      }
    }
  }
  __syncthreads();

  if (tid < 64) {                  // 64-bin chunk sums
    int s = 0;
    for (int jj = 0; jj < 64; ++jj) s += lh[tid * 64 + jj];
    part[tid] = s;
  }
  __syncthreads();
  if (tid == 0) {                  // top threshold bin
    int cum = 0, c = 63;
    for (; c > 0; --c) { if (cum + part[c] >= K) break; cum += part[c]; }
    int hh = c * 64 + 63;
    for (;; --hh) { cum += lh[hh]; if (cum >= K || hh == 0) break; }
    hHi = hh;
  }
  if (tid == 1) {                  // bottom threshold bin
    int cum = 0, c = 0;
    for (; c < 63; ++c) { if (cum + part[c] >= K) break; cum += part[c]; }
    int hl = c * 64;
    for (;; ++hl) { cum += lh[hl]; if (cum >= K || hl == NBIN - 1) break; }
    hLo = hl;
  }
  __syncthreads();
  int hi = hHi, lo = hLo;

  // pass 2: compact from registers (no memory re-read)
#pragma unroll
  for (int j = 0; j < MAXJ; ++j) {
    int f4 = j * 1024 + tid;
    if (j * 4096 < N && f4 * 4 < N) {
      int n0 = f4 * 4;
      float ss[4] = {v4[j].x, v4[j].y, v4[j].z, v4[j].w};
#pragma unroll
      for (int c = 0; c < 4; ++c) {
        if (n0 + c < N) {
          float s = ss[c];
          int bi = (int)((s + R) * invW);
          bi = bi < 0 ? 0 : (bi > NBIN - 1 ? NBIN - 1 : bi);
          if (bi >= hi) { int i = atomicAdd(&cntP, 1); if (i < CAP) candP[i] = packMax(s, n0 + c); }
          if (bi <= lo) { int i = atomicAdd(&cntN, 1); if (i < CAP) candN[i] = packMax(s, n0 + c) ^ 0xFFFFFFFFull; }
        }
      }
    }
  }
  __syncthreads();

  // exact rank, O(C^2); keys unique -> ranks unique & complete
  int tP = cntP < CAP ? cntP : CAP;
  int tN = cntN < CAP ? cntN : CAP;
  int* pos = out + (size_t)b * K;
  int* neg = out + (size_t)B * K + (size_t)b * K;
  for (int i = tid; i < tP; i += 1024) {
    u64 key = candP[i]; int r = 0;
    for (int jj = 0; jj < tP; ++jj) r += (candP[jj] > key);
    if (r < K) pos[r] = (int)(~(unsigned)key);
  }
  for (int i = tid; i < tN; i += 1024) {
    u64 key = candN[i]; int r = 0;
    for (int jj = 0; jj < tN; ++jj) r += (candN[jj] < key);
    if (r < K) neg[r] = (int)(unsigned)key;
  }
}

extern "C" void kernel_launch(void* const* d_in, const int* in_sizes, int n_in,
                              void* d_out, int out_size, void* d_ws, size_t ws_size,
                              hipStream_t stream) {
  const float* basket = (const float*)d_in[0];
  const float* item   = (const float*)d_in[1];
  const float* Wb     = (const float*)d_in[2];
  const float* Wi     = (const float*)d_in[3];
  const float* v      = (const float*)d_in[4];
  int D = in_sizes[4];           // 64
  int B = in_sizes[0] / D;       // 128
  int N = in_sizes[1] / D;       // 50000
  int K = out_size / (2 * B);    // 50

  float* scores = (float*)d_ws;                         // B*N floats = 25.6 MB
  float* ipE    = scores + (size_t)B * N;               // N*64 floats = 12.8 MB
  float* bpE    = ipE + (size_t)N * 64;                 // B*64 floats = 32 KB

  int nItemBlk = (N + 127) / 128;
  int nBB = (B * 64 + 4095) / 4096;
  prep_kernel<<<dim3(nItemBlk + nBB), dim3(256), 0, stream>>>(basket, item, Wb, Wi, ipE, bpE, N, B, nItemBlk);

  dim3 gs((N + 255) / 256, (B + BT - 1) / BT);
  scores_kernel<<<gs, dim3(256), 0, stream>>>(ipE, bpE, v, scores, N, B);

  select_kernel<<<dim3(B), dim3(1024), 0, stream>>>(scores, v, (int*)d_out, N, B, K);
}

// Round 7
// 96.334 us; speedup vs baseline: 1.5147x; 1.3580x over previous
//
#include <hip/hip_runtime.h>

typedef unsigned long long u64;

#define CSC 2.8853900817779268f   // 2*log2(e): tanh(x) = 1 - 2/(exp2(x*CSC)+1)
#define NBIN 4096
#define CAP  256
#define BT   16
#define MAXJ 16                   // select supports N <= 16*4096

// ---------- sortable key packing ----------
__device__ __forceinline__ unsigned ord32(float f) {
  unsigned u = __float_as_uint(f);
  return (u & 0x80000000u) ? ~u : (u | 0x80000000u);
}
// max-key: descending score, ties -> ascending index (jax.lax.top_k semantics)
__device__ __forceinline__ u64 packMax(float f, int n) {
  return ((u64)ord32(f) << 32) | (unsigned)(~(unsigned)n);
}

// ================= prep: 4x4 register-tiled projection, E = exp2(CSC*proj) =================
// Each block: 64 rows (items or baskets) x 64 d. Thread (ti,td) owns 4 rows x 4 d.
// LDS: row-tile transposed itS[e][i], W transposed WT[e][d] -> 2 x ds_read_b128 per 16 FMA.
__global__ void __launch_bounds__(256)
prep_kernel(const float* __restrict__ basket, const float* __restrict__ item,
            const float* __restrict__ Wb, const float* __restrict__ Wi,
            float* __restrict__ ipE, float* __restrict__ bpE,
            int N, int B, int nItemBlk) {
  __shared__ float itS[64][64];   // [e][row]
  __shared__ float WT[64][64];    // [e][d]
  int tid = threadIdx.x;

  bool isBasket = (blockIdx.x >= nItemBlk);
  const float* src = isBasket ? basket : item;
  const float* W   = isBasket ? Wb : Wi;
  float* dst       = isBasket ? bpE : ipE;
  int r0   = isBasket ? (blockIdx.x - nItemBlk) * 64 : blockIdx.x * 64;
  int rMax = isBasket ? B : N;

  // stage row tile (transposed) and W (transposed)
  {
    int r = tid & 63, ec = (tid >> 6) * 16;       // 16 e's per thread
    const float4* sp = (const float4*)(src + (size_t)(r0 + r) * 64 + ec);
    bool ok = (r0 + r) < rMax;
#pragma unroll
    for (int q = 0; q < 4; ++q) {
      float4 t = ok ? sp[q] : make_float4(0.f, 0.f, 0.f, 0.f);
      itS[ec + 4 * q + 0][r] = t.x;
      itS[ec + 4 * q + 1][r] = t.y;
      itS[ec + 4 * q + 2][r] = t.z;
      itS[ec + 4 * q + 3][r] = t.w;
    }
    const float4* wp = (const float4*)(W + (size_t)r * 64 + ec);
#pragma unroll
    for (int q = 0; q < 4; ++q) {
      float4 t = wp[q];
      WT[ec + 4 * q + 0][r] = t.x;
      WT[ec + 4 * q + 1][r] = t.y;
      WT[ec + 4 * q + 2][r] = t.z;
      WT[ec + 4 * q + 3][r] = t.w;
    }
  }
  __syncthreads();

  int ti = tid & 15, td = tid >> 4;               // 16 x 16 thread grid
  float acc[4][4];
#pragma unroll
  for (int i = 0; i < 4; ++i)
#pragma unroll
    for (int j = 0; j < 4; ++j) acc[i][j] = 0.f;

#pragma unroll 8
  for (int e = 0; e < 64; ++e) {
    float4 ri = *(const float4*)&itS[e][4 * ti];
    float4 wd = *(const float4*)&WT[e][4 * td];
    float rr[4] = {ri.x, ri.y, ri.z, ri.w};
    float ww[4] = {wd.x, wd.y, wd.z, wd.w};
#pragma unroll
    for (int i = 0; i < 4; ++i)
#pragma unroll
      for (int j = 0; j < 4; ++j) acc[i][j] = fmaf(rr[i], ww[j], acc[i][j]);
  }

#pragma unroll
  for (int i = 0; i < 4; ++i) {
    int gr = r0 + 4 * ti + i;
    if (gr < rMax) {
      float4 o;
      o.x = __builtin_amdgcn_exp2f(acc[i][0] * CSC);
      o.y = __builtin_amdgcn_exp2f(acc[i][1] * CSC);
      o.z = __builtin_amdgcn_exp2f(acc[i][2] * CSC);
      o.w = __builtin_amdgcn_exp2f(acc[i][3] * CSC);
      *(float4*)(dst + (size_t)gr * 64 + 4 * td) = o;
    }
  }
}

// ================= scores: round-6 structure (unchanged numerics) =================
__global__ void __launch_bounds__(256)
scores_kernel(const float* __restrict__ ipE, const float* __restrict__ bpE,
              const float* __restrict__ v, float* __restrict__ scores, int N, int B) {
  int tid = threadIdx.x;
  int b0 = blockIdx.y * BT;
  if (b0 > B - BT) b0 = B - BT;              // duplicate-safe clamp
  int n = blockIdx.x * 256 + tid;
  if (n >= N) return;

  float ei[64];
  const float4* p = (const float4*)(ipE + (size_t)n * 64);
#pragma unroll
  for (int i = 0; i < 16; ++i) {
    float4 t = p[i];
    ei[4 * i] = t.x; ei[4 * i + 1] = t.y; ei[4 * i + 2] = t.z; ei[4 * i + 3] = t.w;
  }

  double sv = 0.0;
#pragma unroll
  for (int d = 0; d < 64; ++d) sv += (double)v[d];   // uniform -> s_load

#pragma unroll 4
  for (int b = 0; b < BT; ++b) {
    const float* eb = bpE + (size_t)(b0 + b) * 64;   // uniform -> s_load_dwordx8
    double acc = 0.0;
#pragma unroll
    for (int g = 0; g < 8; ++g) {                    // f64 fold every 8 d
      float gs = 0.f;
#pragma unroll
      for (int pp = 0; pp < 4; ++pp) {               // pairs (d0, d0+1)
        int d0 = g * 8 + pp * 2, d1 = d0 + 1;
        float x0 = fmaf(eb[d0], ei[d0], 1.0f);       // 1 + exp2(b+i) via product
        float x1 = fmaf(eb[d1], ei[d1], 1.0f);
        float den = x0 * x1;
        float num = v[d0] * x1;
        num = fmaf(v[d1], x0, num);                  // v0*x1 + v1*x0
        float r = __builtin_amdgcn_rcpf(den);        // 1 rcp per 2 terms
        gs = fmaf(num, r, gs);
      }
      acc += (double)gs;
    }
    scores[(size_t)(b0 + b) * N + n] = (float)(sv - 2.0 * acc);
  }
}

// ================= select: whole pipeline in ONE kernel (1 block = 1 row) =================
__global__ void __launch_bounds__(1024)
select_kernel(const float* __restrict__ scores, const float* __restrict__ v,
              int* __restrict__ out, int N, int B, int K) {
  __shared__ int lh[NBIN];
  __shared__ int part[64];
  __shared__ u64 candP[CAP], candN[CAP];
  __shared__ int cntP, cntN, hHi, hLo;
  int tid = threadIdx.x, b = blockIdx.x;
  const float* row = scores + (size_t)b * N;

  for (int i = tid; i < NBIN; i += 1024) lh[i] = 0;
  if (tid == 0) { cntP = 0; cntN = 0; }

  // |score| < R = sum|v_d| strictly (|tanh|<1) -> linear bins over [-R, R]
  float R = 0.f;
#pragma unroll
  for (int d = 0; d < 64; ++d) R += fabsf(v[d]);     // uniform
  float invW = (float)NBIN / (2.f * R);
  __syncthreads();

  // pass 1: load into REGISTERS + histogram
  float4 v4[MAXJ];
#pragma unroll
  for (int j = 0; j < MAXJ; ++j) {
    int f4 = j * 1024 + tid;
    if (j * 4096 < N && f4 * 4 < N) {
      float4 s4 = *(const float4*)(row + (size_t)f4 * 4);
      v4[j] = s4;
      int n0 = f4 * 4;
      float ss[4] = {s4.x, s4.y, s4.z, s4.w};
#pragma unroll
      for (int c = 0; c < 4; ++c) {
        if (n0 + c < N) {
          int bi = (int)((ss[c] + R) * invW);
          bi = bi < 0 ? 0 : (bi > NBIN - 1 ? NBIN - 1 : bi);
          atomicAdd(&lh[bi], 1);
        }
      }
    }
  }
  __syncthreads();

  if (tid < 64) {                  // 64-bin chunk sums
    int s = 0;
    for (int jj = 0; jj < 64; ++jj) s += lh[tid * 64 + jj];
    part[tid] = s;
  }
  __syncthreads();
  if (tid == 0) {                  // top threshold bin
    int cum = 0, c = 63;
    for (; c > 0; --c) { if (cum + part[c] >= K) break; cum += part[c]; }
    int hh = c * 64 + 63;
    for (;; --hh) { cum += lh[hh]; if (cum >= K || hh == 0) break; }
    hHi = hh;
  }
  if (tid == 1) {                  // bottom threshold bin
    int cum = 0, c = 0;
    for (; c < 63; ++c) { if (cum + part[c] >= K) break; cum += part[c]; }
    int hl = c * 64;
    for (;; ++hl) { cum += lh[hl]; if (cum >= K || hl == NBIN - 1) break; }
    hLo = hl;
  }
  __syncthreads();
  int hi = hHi, lo = hLo;

  // pass 2: compact from registers (no memory re-read)
#pragma unroll
  for (int j = 0; j < MAXJ; ++j) {
    int f4 = j * 1024 + tid;
    if (j * 4096 < N && f4 * 4 < N) {
      int n0 = f4 * 4;
      float ss[4] = {v4[j].x, v4[j].y, v4[j].z, v4[j].w};
#pragma unroll
      for (int c = 0; c < 4; ++c) {
        if (n0 + c < N) {
          float s = ss[c];
          int bi = (int)((s + R) * invW);
          bi = bi < 0 ? 0 : (bi > NBIN - 1 ? NBIN - 1 : bi);
          if (bi >= hi) { int i = atomicAdd(&cntP, 1); if (i < CAP) candP[i] = packMax(s, n0 + c); }
          if (bi <= lo) { int i = atomicAdd(&cntN, 1); if (i < CAP) candN[i] = packMax(s, n0 + c) ^ 0xFFFFFFFFull; }
        }
      }
    }
  }
  __syncthreads();

  // exact rank, O(C^2); keys unique -> ranks unique & complete
  int tP = cntP < CAP ? cntP : CAP;
  int tN = cntN < CAP ? cntN : CAP;
  int* pos = out + (size_t)b * K;
  int* neg = out + (size_t)B * K + (size_t)b * K;
  for (int i = tid; i < tP; i += 1024) {
    u64 key = candP[i]; int r = 0;
    for (int jj = 0; jj < tP; ++jj) r += (candP[jj] > key);
    if (r < K) pos[r] = (int)(~(unsigned)key);
  }
  for (int i = tid; i < tN; i += 1024) {
    u64 key = candN[i]; int r = 0;
    for (int jj = 0; jj < tN; ++jj) r += (candN[jj] < key);
    if (r < K) neg[r] = (int)(unsigned)key;
  }
}

extern "C" void kernel_launch(void* const* d_in, const int* in_sizes, int n_in,
                              void* d_out, int out_size, void* d_ws, size_t ws_size,
                              hipStream_t stream) {
  const float* basket = (const float*)d_in[0];
  const float* item   = (const float*)d_in[1];
  const float* Wb     = (const float*)d_in[2];
  const float* Wi     = (const float*)d_in[3];
  const float* v      = (const float*)d_in[4];
  int D = in_sizes[4];           // 64
  int B = in_sizes[0] / D;       // 128
  int N = in_sizes[1] / D;       // 50000
  int K = out_size / (2 * B);    // 50

  float* scores = (float*)d_ws;                         // B*N floats = 25.6 MB
  float* ipE    = scores + (size_t)B * N;               // N*64 floats = 12.8 MB
  float* bpE    = ipE + (size_t)N * 64;                 // B*64 floats = 32 KB

  int nItemBlk = (N + 63) / 64;
  int nBasBlk  = (B + 63) / 64;
  prep_kernel<<<dim3(nItemBlk + nBasBlk), dim3(256), 0, stream>>>(basket, item, Wb, Wi, ipE, bpE, N, B, nItemBlk);

  dim3 gs((N + 255) / 256, (B + BT - 1) / BT);
  scores_kernel<<<gs, dim3(256), 0, stream>>>(ipE, bpE, v, scores, N, B);

  select_kernel<<<dim3(B), dim3(1024), 0, stream>>>(scores, v, (int*)d_out, N, B, K);
}